// Round 1
// 1212.225 us; speedup vs baseline: 1.2891x; 1.2891x over previous
//
#include <hip/hip_runtime.h>
#include <math.h>

#define N_NODES 10000
#define DIN 128
#define HID 32
#define EMB 16

#define TBS 256                         // threads per block (softmax kernel)
#define RB 4                            // rows per block (10000 % 4 == 0)
#define NF4 2500                        // N_NODES / 4
#define NIT ((NF4 + TBS - 1) / TBS)     // 10 chunk iterations
#define NB (N_NODES / RB)               // 2500 blocks

typedef float fx4 __attribute__((ext_vector_type(4)));

// ---------------- encoder: H = relu(X@W1+b1)@W2+b2 ; Hn = H/||H|| -----------
__global__ __launch_bounds__(256) void encoder_kernel(
    const float* __restrict__ X, const float* __restrict__ W1,
    const float* __restrict__ b1, const float* __restrict__ W2,
    const float* __restrict__ b2, float* __restrict__ Hout,
    float* __restrict__ Hn)
{
    __shared__ float sW1[DIN * HID];
    __shared__ float sW2[HID * EMB];
    __shared__ float sb1[HID];
    __shared__ float sb2[EMB];
    const int t = threadIdx.x;
    for (int k = t; k < DIN * HID; k += 256) sW1[k] = W1[k];
    for (int k = t; k < HID * EMB; k += 256) sW2[k] = W2[k];
    if (t < HID) sb1[t] = b1[t];
    if (t < EMB) sb2[t] = b2[t];
    __syncthreads();

    const int row = blockIdx.x * 256 + t;
    if (row >= N_NODES) return;

    float h1[HID];
#pragma unroll
    for (int h = 0; h < HID; ++h) h1[h] = sb1[h];

    const float4* xr = (const float4*)(X + (size_t)row * DIN);
#pragma unroll
    for (int k4 = 0; k4 < DIN / 4; ++k4) {
        float4 xv = xr[k4];
        const float* w = &sW1[(k4 * 4) * HID];
#pragma unroll
        for (int h = 0; h < HID; ++h) h1[h] = fmaf(xv.x, w[h], h1[h]);
#pragma unroll
        for (int h = 0; h < HID; ++h) h1[h] = fmaf(xv.y, w[HID + h], h1[h]);
#pragma unroll
        for (int h = 0; h < HID; ++h) h1[h] = fmaf(xv.z, w[2 * HID + h], h1[h]);
#pragma unroll
        for (int h = 0; h < HID; ++h) h1[h] = fmaf(xv.w, w[3 * HID + h], h1[h]);
    }

    float e[EMB];
#pragma unroll
    for (int j = 0; j < EMB; ++j) e[j] = sb2[j];
#pragma unroll
    for (int h = 0; h < HID; ++h) {
        float v = fmaxf(h1[h], 0.0f);
#pragma unroll
        for (int j = 0; j < EMB; ++j) e[j] = fmaf(v, sW2[h * EMB + j], e[j]);
    }

    float s = 0.0f;
#pragma unroll
    for (int j = 0; j < EMB; ++j) s = fmaf(e[j], e[j], s);
    float nrm = sqrtf(s);
    float inv = 1.0f / fmaxf(nrm, 1e-12f);

    float* ho = Hout + (size_t)row * EMB;
    float* hn = Hn + (size_t)row * EMB;
#pragma unroll
    for (int j = 0; j < EMB; ++j) ho[j] = e[j];
#pragma unroll
    for (int j = 0; j < EMB; ++j) hn[j] = e[j] * inv;
}

// ---------------- fused logits + row softmax over N×N --------------------
// Key identity: x = alpha*log(a+1e-12) + cl*dot, with a<=1 and dot<=1,
// so x <= cl. Softmax is shift-invariant -> shift by the CONSTANT cl:
//   e = exp(x - cl) in (0, 1]; diagonal (dot=1) keeps sum >= ~1e-3.
// => no max pass, no per-element state, pure streaming recompute.

__device__ __forceinline__ float dot16u(const float* h, const fx4& b0,
                                        const fx4& b1, const fx4& b2,
                                        const fx4& b3)
{
    float s = h[0] * b0.x;
    s = fmaf(h[1],  b0.y, s);
    s = fmaf(h[2],  b0.z, s);
    s = fmaf(h[3],  b0.w, s);
    s = fmaf(h[4],  b1.x, s);
    s = fmaf(h[5],  b1.y, s);
    s = fmaf(h[6],  b1.z, s);
    s = fmaf(h[7],  b1.w, s);
    s = fmaf(h[8],  b2.x, s);
    s = fmaf(h[9],  b2.y, s);
    s = fmaf(h[10], b2.z, s);
    s = fmaf(h[11], b2.w, s);
    s = fmaf(h[12], b3.x, s);
    s = fmaf(h[13], b3.y, s);
    s = fmaf(h[14], b3.z, s);
    s = fmaf(h[15], b3.w, s);
    return s;
}

__global__ __launch_bounds__(TBS, 4) void softmax_kernel(
    const float* __restrict__ A, const float* __restrict__ Hn,
    const float* __restrict__ p_log_tau, const float* __restrict__ p_raw_alpha,
    float* __restrict__ Wout)
{
    const int t = threadIdx.x;
    const int row0 = blockIdx.x * RB;

    const float tau = fminf(fmaxf(__expf(p_log_tau[0]), 0.1f), 10.0f);
    const float alpha = 1.0f / (1.0f + __expf(-p_raw_alpha[0]));
    const float cl = (1.0f - alpha) / tau;

    // Block-uniform query rows -> force into SGPRs (frees ~64 VGPRs).
    float shi[RB][EMB];
#pragma unroll
    for (int r = 0; r < RB; ++r) {
        const fx4* hp = (const fx4*)(Hn + (size_t)(row0 + r) * EMB);
#pragma unroll
        for (int p = 0; p < 4; ++p) {
            fx4 v = hp[p];
            shi[r][4 * p + 0] = __int_as_float(__builtin_amdgcn_readfirstlane(__float_as_int(v.x)));
            shi[r][4 * p + 1] = __int_as_float(__builtin_amdgcn_readfirstlane(__float_as_int(v.y)));
            shi[r][4 * p + 2] = __int_as_float(__builtin_amdgcn_readfirstlane(__float_as_int(v.z)));
            shi[r][4 * p + 3] = __int_as_float(__builtin_amdgcn_readfirstlane(__float_as_int(v.w)));
        }
    }

    const fx4* Hn4 = (const fx4*)Hn;

    // ---- pass 1: row sums of e = exp(x - cl) (A read stays cached) ----
    float sloc[RB];
#pragma unroll
    for (int r = 0; r < RB; ++r) sloc[r] = 0.0f;

#pragma unroll 2
    for (int it = 0; it < NIT; ++it) {
        const int f4 = it * TBS + t;
        if (f4 < NF4) {
            fx4 av[RB];
#pragma unroll
            for (int r = 0; r < RB; ++r)
                av[r] = *((const fx4*)(A + (size_t)(row0 + r) * N_NODES) + f4);
#pragma unroll
            for (int d = 0; d < 4; ++d) {
                const int j = f4 * 4 + d;
                const fx4 b0 = Hn4[j * 4 + 0];
                const fx4 b1 = Hn4[j * 4 + 1];
                const fx4 b2 = Hn4[j * 4 + 2];
                const fx4 b3 = Hn4[j * 4 + 3];
#pragma unroll
                for (int r = 0; r < RB; ++r) {
                    float a = (d == 0) ? av[r].x
                            : (d == 1) ? av[r].y
                            : (d == 2) ? av[r].z
                                       : av[r].w;
                    float lgm = fmaf(alpha, __logf(a + 1e-12f), -cl);
                    float dv = dot16u(shi[r], b0, b1, b2, b3);
                    sloc[r] += __expf(fmaf(cl, dv, lgm));
                }
            }
        }
    }

    // ---- block reduction: sum per row ----
    __shared__ float red[RB][TBS / 64];
    __shared__ float rbc[RB];
    const int lane = t & 63;
    const int wave = t >> 6;
#pragma unroll
    for (int r = 0; r < RB; ++r) {
        float v = sloc[r];
#pragma unroll
        for (int off = 32; off >= 1; off >>= 1) v += __shfl_down(v, off, 64);
        if (lane == 0) red[r][wave] = v;
    }
    __syncthreads();
    if (t < RB) {
        float v = red[t][0];
#pragma unroll
        for (int w = 1; w < TBS / 64; ++w) v += red[t][w];
        rbc[t] = 1.0f / v;
    }
    __syncthreads();
    float invl[RB];
#pragma unroll
    for (int r = 0; r < RB; ++r) invl[r] = rbc[r];

    // ---- pass 2: recompute e, write normalized (reverse order: tail of A
    //      is still L2/L3-hot from pass 1) ----
#pragma unroll 2
    for (int it = NIT - 1; it >= 0; --it) {
        const int f4 = it * TBS + t;
        if (f4 < NF4) {
            fx4 av[RB];
#pragma unroll
            for (int r = 0; r < RB; ++r)
                av[r] = __builtin_nontemporal_load(
                    (const fx4*)(A + (size_t)(row0 + r) * N_NODES) + f4);
            fx4 o[RB];
#pragma unroll
            for (int d = 0; d < 4; ++d) {
                const int j = f4 * 4 + d;
                const fx4 b0 = Hn4[j * 4 + 0];
                const fx4 b1 = Hn4[j * 4 + 1];
                const fx4 b2 = Hn4[j * 4 + 2];
                const fx4 b3 = Hn4[j * 4 + 3];
#pragma unroll
                for (int r = 0; r < RB; ++r) {
                    float a = (d == 0) ? av[r].x
                            : (d == 1) ? av[r].y
                            : (d == 2) ? av[r].z
                                       : av[r].w;
                    float lgm = fmaf(alpha, __logf(a + 1e-12f), -cl);
                    float dv = dot16u(shi[r], b0, b1, b2, b3);
                    float e = __expf(fmaf(cl, dv, lgm)) * invl[r];
                    if (d == 0)      o[r].x = e;
                    else if (d == 1) o[r].y = e;
                    else if (d == 2) o[r].z = e;
                    else             o[r].w = e;
                }
            }
#pragma unroll
            for (int r = 0; r < RB; ++r)
                __builtin_nontemporal_store(
                    o[r], (fx4*)(Wout + (size_t)(row0 + r) * N_NODES) + f4);
        }
    }
}

extern "C" void kernel_launch(void* const* d_in, const int* in_sizes, int n_in,
                              void* d_out, int out_size, void* d_ws, size_t ws_size,
                              hipStream_t stream) {
    const float* X        = (const float*)d_in[0];
    const float* A        = (const float*)d_in[1];
    const float* W1       = (const float*)d_in[2];
    const float* b1       = (const float*)d_in[3];
    const float* W2       = (const float*)d_in[4];
    const float* b2       = (const float*)d_in[5];
    const float* log_tau  = (const float*)d_in[6];
    const float* raw_alpha= (const float*)d_in[7];

    float* Wout = (float*)d_out;
    float* Hout = (float*)d_out + (size_t)N_NODES * N_NODES;
    float* Hn   = (float*)d_ws;   // 10000*16 floats = 640 KB scratch

    encoder_kernel<<<(N_NODES + 255) / 256, 256, 0, stream>>>(X, W1, b1, W2, b2, Hout, Hn);

    softmax_kernel<<<NB, TBS, 0, stream>>>(A, Hn, log_tau, raw_alpha, Wout);
}